// Round 13
// baseline (179.479 us; speedup 1.0000x reference)
//
#include <hip/hip_runtime.h>

// MoE dense: N=16384, D=256, E=8, H=128.
// R13: R12 + the missing __syncthreads() after Xs/gsa staging (R12 raced:
// expert-0 L1 read Xs before global_load_lds drained -> absmax 2e-2).
// Fused experts: weights DIRECT global->VGPR (L2-resident, no staging
// barriers), 64 rows x 4 experts/block, grid (256,2) = 2 blocks/CU,
// expert sum via 2 fp32 partials + k_add2.
// Workspace (~44.6 MB):
//   xb   [16384][256] bf16 @ 0
//   w1t  [8][256][256] bf16 @ 8388608   (w1t[e][h][k] = W1[e][k][h])
//   wg1t [128][256] bf16 @ 9437184      (wg1t[h][k] = Wg1[k][h])
//   w2te [8][256][256] bf16 @ 9502720   (w2te[e][d][h] = W2[e][h][d])
//   g    [16384][8] f32 @ 10551296
//   parts[2][16384][256] f32 @ 11075584

typedef unsigned short USH;
typedef float f32x4 __attribute__((ext_vector_type(4)));
typedef __bf16 bf16x8 __attribute__((ext_vector_type(8)));

#define AS1 __attribute__((address_space(1)))
#define AS3 __attribute__((address_space(3)))

__device__ __forceinline__ USH f2bf(float f) {
  unsigned int u = __float_as_uint(f);
  u += 0x7fffu + ((u >> 16) & 1u);   // RNE
  return (USH)(u >> 16);
}

__device__ __forceinline__ void gl2lds16(const void* g, void* l) {
  __builtin_amdgcn_global_load_lds((AS1 const void*)g, (AS3 void*)l, 16, 0, 0);
}

// ---------------- prep (unchanged) ----------------

__global__ __launch_bounds__(256) void k_prep(
    const float* __restrict__ x,
    const float* __restrict__ Wg1,
    const float* __restrict__ W1,
    const float* __restrict__ W2,
    USH* __restrict__ xb, USH* __restrict__ wg1t,
    USH* __restrict__ w1t, USH* __restrict__ w2te) {
  __shared__ float T[64][65];
  int b = blockIdx.x, tid = threadIdx.x;

  if (b < 2048) {               // xb: flat coalesced cast
    size_t i8 = ((size_t)b * 256 + tid) * 8;
    float4 a = *(const float4*)(x + i8);
    float4 c = *(const float4*)(x + i8 + 4);
    USH v[8];
    v[0] = f2bf(a.x); v[1] = f2bf(a.y); v[2] = f2bf(a.z); v[3] = f2bf(a.w);
    v[4] = f2bf(c.x); v[5] = f2bf(c.y); v[6] = f2bf(c.z); v[7] = f2bf(c.w);
    *(uint4*)(xb + i8) = *(const uint4*)v;
  } else if (b < 2176) {        // w1t[e][h][k] = W1[e][k][h]
    int bp = b - 2048;
    int e = bp >> 4, tl = bp & 15;
    int c0 = (tl >> 2) * 64, h0 = (tl & 3) * 64;
    const float* src = W1 + (size_t)e * 65536;
#pragma unroll
    for (int p = 0; p < 4; ++p) {
      int r = p * 16 + (tid >> 4), d4 = (tid & 15) * 4;
      float4 v = *(const float4*)(src + (size_t)(c0 + r) * 256 + h0 + d4);
      T[r][d4] = v.x; T[r][d4 + 1] = v.y; T[r][d4 + 2] = v.z; T[r][d4 + 3] = v.w;
    }
    __syncthreads();
#pragma unroll
    for (int p = 0; p < 4; ++p) {
      int hr = p * 16 + (tid >> 4), c4 = (tid & 15) * 4;
      USH w[4];
#pragma unroll
      for (int j = 0; j < 4; ++j) w[j] = f2bf(T[c4 + j][hr]);
      *(uint2*)(w1t + (size_t)e * 65536 + (size_t)(h0 + hr) * 256 + c0 + c4) = *(const uint2*)w;
    }
  } else if (b < 2184) {        // wg1t[h][k] = Wg1[k][h]
    int bp = b - 2176;
    int c0 = (bp >> 1) * 64, h0 = (bp & 1) * 64;
#pragma unroll
    for (int p = 0; p < 4; ++p) {
      int r = p * 16 + (tid >> 4), d4 = (tid & 15) * 4;
      float4 v = *(const float4*)(Wg1 + (size_t)(c0 + r) * 128 + h0 + d4);
      T[r][d4] = v.x; T[r][d4 + 1] = v.y; T[r][d4 + 2] = v.z; T[r][d4 + 3] = v.w;
    }
    __syncthreads();
#pragma unroll
    for (int p = 0; p < 4; ++p) {
      int hr = p * 16 + (tid >> 4), c4 = (tid & 15) * 4;
      USH w[4];
#pragma unroll
      for (int j = 0; j < 4; ++j) w[j] = f2bf(T[c4 + j][hr]);
      *(uint2*)(wg1t + (size_t)(h0 + hr) * 256 + c0 + c4) = *(const uint2*)w;
    }
  } else {                      // w2te[e][d][h] = W2[e][h][d]
    int bp = b - 2184;
    int e = bp >> 4, tl = bp & 15;
    int h0 = (tl >> 2) * 64, d0 = (tl & 3) * 64;
    const float* src = W2 + (size_t)e * 65536;
#pragma unroll
    for (int p = 0; p < 4; ++p) {
      int r = p * 16 + (tid >> 4), d4 = (tid & 15) * 4;
      float4 v = *(const float4*)(src + (size_t)(h0 + r) * 256 + d0 + d4);
      T[r][d4] = v.x; T[r][d4 + 1] = v.y; T[r][d4 + 2] = v.z; T[r][d4 + 3] = v.w;
    }
    __syncthreads();
#pragma unroll
    for (int p = 0; p < 4; ++p) {
      int dr = p * 16 + (tid >> 4), h4 = (tid & 15) * 4;
      USH w[4];
#pragma unroll
      for (int j = 0; j < 4; ++j) w[j] = f2bf(T[h4 + j][dr]);
      *(uint2*)(w2te + (size_t)e * 65536 + (size_t)(d0 + dr) * 256 + h0 + h4) = *(const uint2*)w;
    }
  }
}

// ---------------- gate (unchanged) ----------------

__global__ __launch_bounds__(256) void k_gate(const USH* __restrict__ xb,
                                              const USH* __restrict__ wg1t,
                                              const float* __restrict__ bg1,
                                              const float* __restrict__ wg2,
                                              const float* __restrict__ bg2,
                                              float* __restrict__ g) {
  __shared__ __align__(16) USH As[32 * 64];
  __shared__ __align__(16) USH Bs[128 * 64];
  __shared__ float hg[32 * 129];
  __shared__ float bg1s[128];
  __shared__ float w2s[128 * 8];
  __shared__ float b2s[8];
  __shared__ float lg[32 * 8];

  int tid = threadIdx.x;
  int wave = tid >> 6, lane = tid & 63;
  int quad = lane >> 4, l16 = lane & 15;
  int sw = l16 & 7;
  int wr = wave >> 1, wc = wave & 1;
  int rowBase = blockIdx.x * 32;

  for (int t = tid; t < 1024; t += 256) w2s[t] = wg2[t];
  if (tid < 8) b2s[tid] = bg2[tid];
  if (tid < 128) bg1s[tid] = bg1[tid];

  f32x4 acc[4] = {};
  for (int kt = 0; kt < 4; ++kt) {
    int kb = kt * 64;
    {
      int r = tid >> 3, c8 = (tid & 7) ^ (r & 7);
      gl2lds16(xb + (size_t)(rowBase + r) * 256 + kb + c8 * 8, As + (size_t)tid * 8);
    }
#pragma unroll
    for (int c = 0; c < 4; ++c) {
      int i = c * 256 + tid;
      int r = i >> 3, c8 = (i & 7) ^ (r & 7);
      gl2lds16(wg1t + (size_t)r * 256 + kb + c8 * 8, Bs + (size_t)i * 8);
    }
    __syncthreads();
#pragma unroll
    for (int kkc = 0; kkc < 8; kkc += 4) {
      bf16x8 av = *(const bf16x8*)(As + (wr * 16 + l16) * 64 + (((kkc + quad) ^ sw) * 8));
#pragma unroll
      for (int j = 0; j < 4; ++j) {
        bf16x8 bv = *(const bf16x8*)(Bs + (wc * 64 + j * 16 + l16) * 64 + (((kkc + quad) ^ sw) * 8));
        acc[j] = __builtin_amdgcn_mfma_f32_16x16x32_bf16(av, bv, acc[j], 0, 0, 0);
      }
    }
    __syncthreads();
  }

#pragma unroll
  for (int j = 0; j < 4; ++j)
#pragma unroll
    for (int r = 0; r < 4; ++r) {
      int row = wr * 16 + quad * 4 + r;
      int col = wc * 64 + j * 16 + l16;
      hg[row * 129 + col] = fmaxf(acc[j][r] + bg1s[col], 0.0f);
    }
  __syncthreads();

  {
    int row = tid >> 3, p = tid & 7;
    float s = b2s[p];
    for (int k = 0; k < 128; ++k) s += hg[row * 129 + k] * w2s[k * 8 + p];
    lg[row * 8 + p] = s;
  }
  __syncthreads();

  if (tid < 32) {
    float l[8];
    float m = -1e30f;
#pragma unroll
    for (int e = 0; e < 8; ++e) { l[e] = lg[tid * 8 + e]; m = fmaxf(m, l[e]); }
    float s = 0.0f;
#pragma unroll
    for (int e = 0; e < 8; ++e) { l[e] = expf(l[e] - m); s += l[e]; }
    float inv = 1.0f / s;
    size_t grow = rowBase + tid;
#pragma unroll
    for (int e = 0; e < 8; ++e) g[grow * 8 + e] = l[e] * inv;
  }
}

// ---------------- fused experts v2 (R13: staging barrier fixed) ----------------

__global__ __launch_bounds__(256) void k_experts(const USH* __restrict__ xb,
                                                 const USH* __restrict__ w1t,
                                                 const USH* __restrict__ w2te,
                                                 const float* __restrict__ g,
                                                 const float* __restrict__ b1,
                                                 const float* __restrict__ b2,
                                                 float* __restrict__ parts) {
  __shared__ __align__(16) USH Xs[64 * 256];   // 32KB
  __shared__ __align__(16) USH Hs[64 * 256];   // 32KB
  __shared__ float gsa[64 * 4];                // g for 4 experts

  int tid = threadIdx.x;
  int wave = tid >> 6, lane = tid & 63;
  int quad = lane >> 4, l16 = lane & 15;
  int sw = l16 & 7;
  int rowBase = blockIdx.x * 64;
  int eh = blockIdx.y;
  float* outp = parts + (size_t)eh * 16384 * 256;

  // stage x once: 64 rows x 32 chunks, slot c^(r&7)
#pragma unroll
  for (int p = 0; p < 8; ++p) {
    int i = p * 256 + tid;
    int r = i >> 5, c = (i & 31) ^ (r & 7);
    gl2lds16(xb + (size_t)(rowBase + r) * 256 + c * 8, Xs + (size_t)i * 8);
  }
  gsa[tid] = g[(size_t)(rowBase + (tid >> 2)) * 8 + eh * 4 + (tid & 3)];
  __syncthreads();   // R13 FIX: Xs staging + gsa must complete before L1 reads

  f32x4 acc_out[4][4] = {};

  for (int el = 0; el < 4; ++el) {
    int e = eh * 4 + el;
    const USH* W1e = w1t + (size_t)e * 65536;
    const USH* W2e = w2te + (size_t)e * 65536;
    float b1v[4], b2v[4];
#pragma unroll
    for (int ct = 0; ct < 4; ++ct) {
      int col = wave * 64 + ct * 16 + l16;
      b1v[ct] = b1[e * 256 + col];
      b2v[ct] = b2[e * 256 + col];
    }

    // ---- L1: h = x @ W1e^T (B direct from global, no barriers) ----
    f32x4 acc_h[4][4] = {};
#pragma unroll
    for (int kt = 0; kt < 8; ++kt) {
      bf16x8 av[4], bv[4];
#pragma unroll
      for (int rt = 0; rt < 4; ++rt)
        av[rt] = *(const bf16x8*)(Xs + ((rt * 16 + l16) * 32 + (((kt * 4 + quad) ^ sw))) * 8);
#pragma unroll
      for (int ct = 0; ct < 4; ++ct)
        bv[ct] = *(const bf16x8*)(W1e + (size_t)(wave * 64 + ct * 16 + l16) * 256 + kt * 32 + quad * 8);
#pragma unroll
      for (int rt = 0; rt < 4; ++rt)
#pragma unroll
        for (int ct = 0; ct < 4; ++ct)
          acc_h[rt][ct] = __builtin_amdgcn_mfma_f32_16x16x32_bf16(av[rt], bv[ct], acc_h[rt][ct], 0, 0, 0);
    }

    __syncthreads();   // prev expert's Hs reads done

    // ---- h' = g*relu(h+b1) -> Hs ----
#pragma unroll
    for (int rt = 0; rt < 4; ++rt)
#pragma unroll
      for (int rr = 0; rr < 4; ++rr) {
        int hr = rt * 16 + quad * 4 + rr;
        float gg = gsa[hr * 4 + el];
#pragma unroll
        for (int ct = 0; ct < 4; ++ct) {
          int col = wave * 64 + ct * 16 + l16;
          float v = fmaxf(acc_h[rt][ct][rr] + b1v[ct], 0.0f) * gg;
          Hs[hr * 256 + (((col >> 3) ^ (hr & 7)) * 8) + (col & 7)] = f2bf(v);
        }
      }
    __syncthreads();

    // ---- L2: acc_out += h' @ W2e^T ----
#pragma unroll
    for (int kt = 0; kt < 8; ++kt) {
      bf16x8 av[4], bv[4];
#pragma unroll
      for (int rt = 0; rt < 4; ++rt)
        av[rt] = *(const bf16x8*)(Hs + ((rt * 16 + l16) * 32 + (((kt * 4 + quad) ^ sw))) * 8);
#pragma unroll
      for (int ct = 0; ct < 4; ++ct)
        bv[ct] = *(const bf16x8*)(W2e + (size_t)(wave * 64 + ct * 16 + l16) * 256 + kt * 32 + quad * 8);
#pragma unroll
      for (int rt = 0; rt < 4; ++rt)
#pragma unroll
        for (int ct = 0; ct < 4; ++ct)
          acc_out[rt][ct] = __builtin_amdgcn_mfma_f32_16x16x32_bf16(av[rt], bv[ct], acc_out[rt][ct], 0, 0, 0);
    }

    // ---- + g*b2 ----
#pragma unroll
    for (int ct = 0; ct < 4; ++ct)
#pragma unroll
      for (int rt = 0; rt < 4; ++rt)
#pragma unroll
        for (int rr = 0; rr < 4; ++rr)
          acc_out[rt][ct][rr] += gsa[(rt * 16 + quad * 4 + rr) * 4 + el] * b2v[ct];
  }

  // ---- store partial ----
#pragma unroll
  for (int rt = 0; rt < 4; ++rt)
#pragma unroll
    for (int rr = 0; rr < 4; ++rr) {
      size_t grow = (size_t)(rowBase + rt * 16 + quad * 4 + rr);
#pragma unroll
      for (int ct = 0; ct < 4; ++ct)
        outp[grow * 256 + wave * 64 + ct * 16 + l16] = acc_out[rt][ct][rr];
    }
}

// ---------------- combine: out = P0 + P1 ----------------

__global__ __launch_bounds__(256) void k_add2(const float* __restrict__ parts,
                                              float* __restrict__ out) {
  size_t i4 = ((size_t)blockIdx.x * 256 + threadIdx.x) * 4;
  float4 a = *(const float4*)(parts + i4);
  float4 b = *(const float4*)(parts + 4194304 + i4);
  float4 o;
  o.x = a.x + b.x; o.y = a.y + b.y; o.z = a.z + b.z; o.w = a.w + b.w;
  *(float4*)(out + i4) = o;
}

// ---------------- launch ----------------

extern "C" void kernel_launch(void* const* d_in, const int* in_sizes, int n_in,
                              void* d_out, int out_size, void* d_ws, size_t ws_size,
                              hipStream_t stream) {
  const float* x   = (const float*)d_in[0];
  const float* Wg1 = (const float*)d_in[1];
  const float* bg1 = (const float*)d_in[2];
  const float* Wg2 = (const float*)d_in[3];
  const float* bg2 = (const float*)d_in[4];
  const float* W1  = (const float*)d_in[5];
  const float* b1  = (const float*)d_in[6];
  const float* W2  = (const float*)d_in[7];
  const float* b2  = (const float*)d_in[8];
  float* out = (float*)d_out;

  char* ws = (char*)d_ws;
  USH*   xb    = (USH*)(ws);
  USH*   w1t   = (USH*)(ws + 8388608);
  USH*   wg1t  = (USH*)(ws + 9437184);
  USH*   w2te  = (USH*)(ws + 9502720);
  float* g     = (float*)(ws + 10551296);
  float* parts = (float*)(ws + 11075584);   // 2 x 16MB; total ~44.6 MB

  hipLaunchKernelGGL(k_prep, dim3(2312), dim3(256), 0, stream,
                     x, Wg1, W1, W2, xb, wg1t, w1t, w2te);
  hipLaunchKernelGGL(k_gate,    dim3(512),      dim3(256), 0, stream, xb, wg1t, bg1, Wg2, bg2, g);
  hipLaunchKernelGGL(k_experts, dim3(256, 2),   dim3(256), 0, stream, xb, w1t, w2te, g, b1, b2, parts);
  hipLaunchKernelGGL(k_add2,    dim3(4096),     dim3(256), 0, stream, parts, out);
}